// Round 3
// baseline (469.323 us; speedup 1.0000x reference)
//
#include <hip/hip_runtime.h>
#include <math.h>

#define PI_F 3.14159265358979323846f

// ---------------------------------------------------------------------------
// Layout: one 128x128 fp32 plane in LDS (4096 float4) + 34-float4 zero
// sentinel region at [4096..4129]. Invalid (OOB) lane reads are redirected to
// sentinel index 4096+(lane&31) (per-lane rotated -> no bank hot-spot), so no
// value-zeroing cndmasks are needed.
// Each thread: 8 output rows x 8 output cols. Per tap: 9 rows x 3 ds_read_b128
// (rolling row reuse), 256 FMAs. Per-(o,t) shift+weights computed per wave
// (lane t owns tap t) and broadcast via v_readlane -> SGPRs.
// ---------------------------------------------------------------------------

__device__ __forceinline__ void rdrow(float (&D)[12], const float4* __restrict__ L,
                                      int rowT, int k, int baseIdx,
                                      bool vb0, bool vb1, bool vb2, int SENTL) {
  bool rv = ((unsigned)(rowT + k)) < 128u;
  int base = baseIdx + k * 32;
  int iA = (rv & vb0) ? base : SENTL;
  int iB = (rv & vb1) ? base : (SENTL - 1);
  int iC = (rv & vb2) ? base : (SENTL - 2);
  float4 a = L[iA];
  float4 b = L[iB + 1];
  float4 c = L[iC + 2];
  D[0] = a.x; D[1] = a.y; D[2]  = a.z; D[3]  = a.w;
  D[4] = b.x; D[5] = b.y; D[6]  = b.z; D[7]  = b.w;
  D[8] = c.x; D[9] = c.y; D[10] = c.z; D[11] = c.w;
}

template <int R>
__device__ __forceinline__ void taprow(float (&a)[8], const float (&T)[12], const float (&B)[12],
                                       float w00, float w01, float w10, float w11) {
#pragma unroll
  for (int i = 0; i < 8; i++) {
    a[i] = fmaf(w00, T[R + i], fmaf(w01, T[R + i + 1],
           fmaf(w10, B[R + i], fmaf(w11, B[R + i + 1], a[i]))));
  }
}

template <int R>
__device__ __forceinline__ void kloopw(float (&acc)[8][8], const float4* __restrict__ L,
                                       int rowT, int baseIdx,
                                       bool vb0, bool vb1, bool vb2, int SENTL,
                                       float w00, float w01, float w10, float w11) {
  float A[12], B[12];
  rdrow(A, L, rowT, 0, baseIdx, vb0, vb1, vb2, SENTL);
#pragma unroll
  for (int kk = 0; kk < 4; kk++) {
    rdrow(B, L, rowT, 2 * kk + 1, baseIdx, vb0, vb1, vb2, SENTL);
    taprow<R>(acc[2 * kk + 0], A, B, w00, w01, w10, w11);
    rdrow(A, L, rowT, 2 * kk + 2, baseIdx, vb0, vb1, vb2, SENTL);
    taprow<R>(acc[2 * kk + 1], B, A, w00, w01, w10, w11);
  }
}

__global__ __launch_bounds__(256, 2)
void pgd_main_kernel(const float* __restrict__ X,
                     const float* __restrict__ offx, const float* __restrict__ offy,
                     const float* __restrict__ ua, const float* __restrict__ us,
                     const float* __restrict__ araw, const float* __restrict__ sraw,
                     float* __restrict__ out) {
  __shared__ float4 L[4130];  // 64 KB plane + 34 float4 zero sentinel
  int p = blockIdx.x;         // plane = b*128 + o*4 + c
  int o = (p & 127) >> 2;
  const float4* __restrict__ xg = (const float4*)(X + (size_t)p * 16384);
  int tid = threadIdx.x;

#pragma unroll
  for (int i = 0; i < 16; i++) L[tid + i * 256] = xg[tid + i * 256];
  if (tid < 34) L[4096 + tid] = make_float4(0.f, 0.f, 0.f, 0.f);

  // ---- per-wave tap params (lane t = lane&15 owns tap t) ----
  int lane = tid & 63;
  int t = lane & 15;
  const float MIN_A = 0.024979197860971382f;   // atan2(0.5,10)/2
  const float MAX_A = PI_F;
  const float MIN_S = 0.2f, MAX_S = 5.0f;
  const float EPS = 1.1920928955078125e-07f;   // np.float32 eps

  float angle_std = 1.0f / (1.0f + expf(-araw[o])) * (MAX_A - MIN_A) + MIN_A;
  float scale_std = 1.0f / (1.0f + expf(-sraw[o])) * (MAX_S - MIN_S) + MIN_S;
  float high_a = fminf(angle_std * 3.0f, PI_F);
  float s3 = scale_std * 3.0f;
  float va = angle_std * angle_std + EPS;
  float vs = scale_std * scale_std + EPS;

  // denominator: each lane computes 2 of the 32 terms, butterfly over 16 lanes
  float a0v = ua[o * 32 + t] * high_a;
  float s0v = us[o * 32 + t] * s3;
  float a1v = ua[o * 32 + t + 16] * high_a;
  float s1v = us[o * 32 + t + 16] * s3;
  float e0 = expf(-(a0v * a0v) * 0.5f / va - (s0v * s0v) * 0.5f / vs);
  float e1 = expf(-(a1v * a1v) * 0.5f / va - (s1v * s1v) * 0.5f / vs);
  float dsum = e0 + e1;
  dsum += __shfl_xor(dsum, 1);
  dsum += __shfl_xor(dsum, 2);
  dsum += __shfl_xor(dsum, 4);
  dsum += __shfl_xor(dsum, 8);
  dsum += EPS;
  float wt = e0 / dsum * 2.0f;   // * NUM_TOTAL/NUM_SAMPLE

  float oxv = offx[o], oyv = offy[o];
  float dist = sqrtf(oxv * oxv + oyv * oyv);
  float ang0 = atan2f(oyv, oxv);
  float ndv = dist + s0v;
  float nav = ang0 + a0v;
  float dxv = ndv * cosf(nav);
  float dyv = ndv * sinf(nav);
  float fxv = floorf(dxv), fyv = floorf(dyv);
  float axv = dxv - fxv, ayv = dyv - fyv;
  int ixL = (int)fxv;
  int iyL = (int)fyv;
  float w00L = wt * (1.0f - ayv) * (1.0f - axv);
  float w01L = wt * (1.0f - ayv) * axv;
  float w10L = wt * ayv * (1.0f - axv);
  float w11L = wt * ayv * axv;

  __syncthreads();

  int wv = tid >> 6;        // 0..3
  int q = lane >> 4;        // 0..3 quarter-wave
  int cc = lane & 15;       // 8-col chunk: cols 8cc..8cc+7
  int g = wv * 4 + q;       // row-group 0..15
  int y0 = g * 8;
  int SENTL = 4096 + (lane & 31);
  float* outp = out + (size_t)p * 16384;

  float acc[8][8];
#pragma unroll
  for (int k = 0; k < 8; k++)
#pragma unroll
    for (int i = 0; i < 8; i++) acc[k][i] = 0.f;

#pragma unroll 1
  for (int tt = 0; tt < 16; tt++) {
    float w00 = __uint_as_float(__builtin_amdgcn_readlane(__float_as_uint(w00L), tt));
    float w01 = __uint_as_float(__builtin_amdgcn_readlane(__float_as_uint(w01L), tt));
    float w10 = __uint_as_float(__builtin_amdgcn_readlane(__float_as_uint(w10L), tt));
    float w11 = __uint_as_float(__builtin_amdgcn_readlane(__float_as_uint(w11L), tt));
    int ix = __builtin_amdgcn_readlane(ixL, tt);
    int iy = __builtin_amdgcn_readlane(iyL, tt);

    int S = ix >> 2;          // wave-uniform (SGPR)
    int r = ix & 3;           // wave-uniform sub-word alignment
    int b0 = 2 * cc + S;      // first needed float4 block (exact floor)
    bool vb0 = ((unsigned)b0) < 32u;
    bool vb1 = ((unsigned)(b0 + 1)) < 32u;
    bool vb2 = ((unsigned)(b0 + 2)) < 32u;
    int rowT = y0 + iy;
    int baseIdx = rowT * 32 + b0;

    switch (r) {
      case 0:  kloopw<0>(acc, L, rowT, baseIdx, vb0, vb1, vb2, SENTL, w00, w01, w10, w11); break;
      case 1:  kloopw<1>(acc, L, rowT, baseIdx, vb0, vb1, vb2, SENTL, w00, w01, w10, w11); break;
      case 2:  kloopw<2>(acc, L, rowT, baseIdx, vb0, vb1, vb2, SENTL, w00, w01, w10, w11); break;
      default: kloopw<3>(acc, L, rowT, baseIdx, vb0, vb1, vb2, SENTL, w00, w01, w10, w11); break;
    }
  }

#pragma unroll
  for (int k = 0; k < 8; k++) {
    float4 s0 = make_float4(acc[k][0], acc[k][1], acc[k][2], acc[k][3]);
    float4 s1 = make_float4(acc[k][4], acc[k][5], acc[k][6], acc[k][7]);
    float* rp = outp + (size_t)(y0 + k) * 128 + 8 * cc;
    *(float4*)(rp + 0) = s0;
    *(float4*)(rp + 4) = s1;
  }
}

extern "C" void kernel_launch(void* const* d_in, const int* in_sizes, int n_in,
                              void* d_out, int out_size, void* d_ws, size_t ws_size,
                              hipStream_t stream) {
  const float* x  = (const float*)d_in[0];
  const float* ox = (const float*)d_in[1];
  const float* oy = (const float*)d_in[2];
  const float* ua = (const float*)d_in[3];
  const float* us = (const float*)d_in[4];
  const float* ar = (const float*)d_in[5];
  const float* sr = (const float*)d_in[6];
  float* out = (float*)d_out;
  (void)d_ws; (void)ws_size; (void)in_sizes; (void)n_in; (void)out_size;

  hipLaunchKernelGGL(pgd_main_kernel, dim3(2048), dim3(256), 0, stream,
                     x, ox, oy, ua, us, ar, sr, out);
}